// Round 1
// 241.498 us; speedup vs baseline: 1.1757x; 1.1757x over previous
//
#include <hip/hip_runtime.h>

#define BM 64
#define BN 64
#define BK 16

typedef float f4 __attribute__((ext_vector_type(4)));

// GEMM with split-K (KS panels). P layout: panel ks occupies rows [ks*1024, ks*1024+1024):
//   rows [ks*1024 + 0,    ks*1024 + 512):  input1 @ W[0:768]   partial (k-slice ks)
//   rows [ks*1024 + 512,  ks*1024 + 1024): input2 @ W[768:1536] partial (+bias only in ks==0)
// Single-barrier double-buffered pipeline: global prefetch issued one full compute
// phase before its consumption; one __syncthreads per BK step.
template<int KS>
__global__ __launch_bounds__(256) void gemm_kernel(
    const float* __restrict__ A1, const float* __restrict__ A2,
    const float* __restrict__ W, const float* __restrict__ bias,
    float* __restrict__ P)
{
    constexpr int KLEN = 768 / KS;
    __shared__ float As[2][BK][BM + 4];
    __shared__ float Bs[2][BK][BN + 4];

    const int bz = blockIdx.z;
    const int z  = bz & 1;        // 0 -> input1, 1 -> input2
    const int ks = bz >> 1;       // k-slice
    const int n0 = blockIdx.x * BN;
    const int m0 = blockIdx.y * BM;
    const int t  = threadIdx.x;

    const float* A = z ? A2 : A1;

    // A tile: thread -> (row, k4), one float4 along k (coalesced)
    const int a_m = t >> 2;              // 0..63
    const int a_k = (t & 3) * 4;         // 0,4,8,12
    // B tile: thread -> (k, col4), float4 along n (coalesced)
    const int b_k = t >> 4;              // 0..15
    const int b_n = (t & 15) * 4;        // 0..60

    const int tm = (t >> 4) * 4;         // micro-tile row base
    const int tn = (t & 15) * 4;         // micro-tile col base

    const float* Aptr = A + (size_t)(m0 + a_m) * 768 + ks * KLEN + a_k;
    const float* Bptr = W + (size_t)(z * 768 + ks * KLEN + b_k) * 768 + n0 + b_n;

    // prologue prefetch (tile 0)
    float4 av = *(const float4*)Aptr;
    float4 bv = *(const float4*)Bptr;

    float acc[4][4] = {};
    int cur = 0;

    #pragma unroll 2
    for (int k0 = 0; k0 < KLEN; k0 += BK) {
        // stage regs -> LDS[cur]
        As[cur][a_k + 0][a_m] = av.x;
        As[cur][a_k + 1][a_m] = av.y;
        As[cur][a_k + 2][a_m] = av.z;
        As[cur][a_k + 3][a_m] = av.w;
        *(float4*)&Bs[cur][b_k][b_n] = bv;
        // issue next tile's loads; they land during this iteration's compute
        if (k0 + BK < KLEN) {
            av = *(const float4*)(Aptr + (k0 + BK));
            bv = *(const float4*)(Bptr + (size_t)(k0 + BK) * 768);
        }
        __syncthreads();   // LDS[cur] visible; also fences reads of LDS[cur^1] from 2 iters ago
        #pragma unroll
        for (int k = 0; k < BK; ++k) {
            const float4 a4 = *(const float4*)&As[cur][k][tm];
            const float4 b4 = *(const float4*)&Bs[cur][k][tn];
            const float ar[4] = {a4.x, a4.y, a4.z, a4.w};
            const float br[4] = {b4.x, b4.y, b4.z, b4.w};
            #pragma unroll
            for (int i = 0; i < 4; ++i)
                #pragma unroll
                for (int j = 0; j < 4; ++j)
                    acc[i][j] += ar[i] * br[j];
        }
        cur ^= 1;
    }

    float4 bb = make_float4(0.f, 0.f, 0.f, 0.f);
    if (z == 1 && ks == 0) bb = *(const float4*)(bias + n0 + tn);

    const int prow0 = ks * 1024 + z * 512 + m0 + tm;
    #pragma unroll
    for (int i = 0; i < 4; ++i) {
        float4 r;
        r.x = acc[i][0] + bb.x;
        r.y = acc[i][1] + bb.y;
        r.z = acc[i][2] + bb.z;
        r.w = acc[i][3] + bb.w;
        *(float4*)(P + (size_t)(prow0 + i) * 768 + n0 + tn) = r;
    }
}

// out[b,n,m,:] = sum_ks P[ks*1024 + b*128+n, :] + sum_ks P[ks*1024 + 512 + b*128+m, :]
// 192 threads cover o=768 as float4; each block does one bn and 32 m rows.
// Non-temporal stores: 201 MB output stream should not thrash L2 (keeps P resident).
template<int KS>
__global__ __launch_bounds__(192) void bcast_kernel(
    const float* __restrict__ P, float* __restrict__ out)
{
    const int t     = threadIdx.x;       // 0..191
    const int bn    = blockIdx.x;        // 0..511 = b*128+n
    const int b     = bn >> 7;
    const int mbase = blockIdx.y * 32;

    f4 p1v = *(const f4*)(P + (size_t)bn * 768 + t * 4);
    if (KS == 2) p1v += *(const f4*)(P + (size_t)(1024 + bn) * 768 + t * 4);

    const float* p2a = P + (size_t)(512 + b * 128) * 768 + t * 4;
    const float* p2b = P + (size_t)(1536 + b * 128) * 768 + t * 4;
    float* obase = out + (size_t)bn * (128 * 768) + t * 4;

    #pragma unroll 8
    for (int mm = 0; mm < 32; ++mm) {
        const int m = mbase + mm;
        f4 v = p1v + *(const f4*)(p2a + (size_t)m * 768);
        if (KS == 2) v += *(const f4*)(p2b + (size_t)m * 768);
        __builtin_nontemporal_store(v, (f4*)(obase + (size_t)m * 768));
    }
}

extern "C" void kernel_launch(void* const* d_in, const int* in_sizes, int n_in,
                              void* d_out, int out_size, void* d_ws, size_t ws_size,
                              hipStream_t stream)
{
    const float* input1 = (const float*)d_in[0];  // (4,128,768)
    const float* input2 = (const float*)d_in[1];  // (4,128,768)
    const float* W      = (const float*)d_in[2];  // (1536,768)
    const float* bias   = (const float*)d_in[3];  // (768,)
    float* out = (float*)d_out;                   // (4,128,128,768)
    float* P   = (float*)d_ws;                    // up to 2048*768 floats = 6.3 MB scratch

    const bool split = ws_size >= (size_t)2048 * 768 * sizeof(float);

    if (split) {
        gemm_kernel<2><<<dim3(768 / BN, 512 / BM, 4), 256, 0, stream>>>(
            input1, input2, W, bias, P);
        bcast_kernel<2><<<dim3(512, 4), 192, 0, stream>>>(P, out);
    } else {
        gemm_kernel<1><<<dim3(768 / BN, 512 / BM, 2), 256, 0, stream>>>(
            input1, input2, W, bias, P);
        bcast_kernel<1><<<dim3(512, 4), 192, 0, stream>>>(P, out);
    }
}